// Round 6
// baseline (189.334 us; speedup 1.0000x reference)
//
#include <hip/hip_runtime.h>
#include <hip/hip_bf16.h>

#define N_ 16
#define D_ 2048
#define H_ 32
#define W_ 32
#define HW_ 1024
#define F_ 512

typedef unsigned short u16;
typedef unsigned int u32;
typedef __attribute__((ext_vector_type(8))) short bf16x8;
typedef __attribute__((ext_vector_type(4))) float f32x4;

__device__ __forceinline__ u16 f2bf(float f) {
  union { float fv; u32 u; } c; c.fv = f;
  u32 u = c.u;
  u32 r = (u + 0x7fffu + ((u >> 16) & 1u)) >> 16;   // RNE
  return (u16)r;
}

#define GLD_LDS16(gp, lp) __builtin_amdgcn_global_load_lds( \
    (const __attribute__((address_space(1))) void*)(gp), \
    (__attribute__((address_space(3))) void*)(lp), 16, 0, 0)

// ---- K0: zero sumsq+gbuf (192 KB contiguous) ----
__global__ __launch_bounds__(256) void k_zero(float* __restrict__ p) {
  int i = blockIdx.x * 256 + threadIdx.x;   // 48 blocks x 256 x float4 = 192 KB
  ((float4*)p)[i] = (float4){0.f, 0.f, 0.f, 0.f};
}

// ---- K1: sum of squares over channel dim -> sumsq[n][hw] (atomic partials) ----
__global__ __launch_bounds__(256) void k_sumsq(const float* __restrict__ x, float* __restrict__ sumsq) {
  const int n = blockIdx.x;        // 16
  const int dc = blockIdx.y;       // 32 chunks x 64 d
  const int t = threadIdx.x;
  const float* xp = x + ((size_t)n * D_ + (size_t)dc * 64) * HW_;
  float s0 = 0.f, s1 = 0.f, s2 = 0.f, s3 = 0.f;
  for (int d = 0; d < 64; ++d) {
    const float* row = xp + (size_t)d * HW_;
    float v0 = row[t], v1 = row[t + 256], v2 = row[t + 512], v3 = row[t + 768];
    s0 += v0 * v0; s1 += v1 * v1; s2 += v2 * v2; s3 += v3 * v3;
  }
  atomicAdd(&sumsq[n * HW_ + t      ], s0);
  atomicAdd(&sumsq[n * HW_ + t + 256], s1);
  atomicAdd(&sumsq[n * HW_ + t + 512], s2);
  atomicAdd(&sumsq[n * HW_ + t + 768], s3);
}

// ---- K2: float4-vectorized separable 3x3 box + GeM partials ----
// grid (n=16, hb=4, dc=32); block 256. thread: w4 = t&7 (w-quad), dg = t>>3 (d-pair).
// 8 output h-rows per block (10 input rows), 2 d's per thread.
__global__ __launch_bounds__(256) void k_box3(const float* __restrict__ x,
    const float* __restrict__ sumsq, const float* __restrict__ pvec,
    float* __restrict__ gbuf, u16* __restrict__ boxT) {
  const int n = blockIdx.x, hb = blockIdx.y, dc = blockIdx.z;
  const int h0 = hb * 8, d0 = dc * 64;
  const int t = threadIdx.x;
  const int w4 = t & 7, wq = w4 * 4, dg = t >> 3;
  const float p = pvec[0];
  const bool p3 = (p == 3.0f);

  __shared__ __align__(16) u32 sbox[256 * 34];   // [hw 256][d-pair 32 pad->34]

  float4 rn[10];
  #pragma unroll
  for (int jj = 0; jj < 10; ++jj) {
    int hp = h0 - 1 + jj;
    if (hp >= 0 && hp < H_) {
      float4 ss = *(const float4*)(sumsq + n * HW_ + hp * W_ + wq);
      rn[jj].x = 1.0f / fmaxf(sqrtf(ss.x), 1e-12f);
      rn[jj].y = 1.0f / fmaxf(sqrtf(ss.y), 1e-12f);
      rn[jj].z = 1.0f / fmaxf(sqrtf(ss.z), 1e-12f);
      rn[jj].w = 1.0f / fmaxf(sqrtf(ss.w), 1e-12f);
    } else {
      rn[jj] = (float4){0.f, 0.f, 0.f, 0.f};
    }
  }

  float gp[2] = {0.f, 0.f};
  #pragma unroll
  for (int dj = 0; dj < 2; ++dj) {
    const int d = d0 + dg * 2 + dj;
    const float* base = x + ((size_t)(n * D_ + d)) * HW_ + wq;
    float4 v[10];
    #pragma unroll
    for (int jj = 0; jj < 10; ++jj) {
      int hp = h0 - 1 + jj;
      if (hp >= 0 && hp < H_) {
        float4 xv = *(const float4*)(base + hp * W_);
        v[jj].x = xv.x * rn[jj].x;
        v[jj].y = xv.y * rn[jj].y;
        v[jj].z = xv.z * rn[jj].z;
        v[jj].w = xv.w * rn[jj].w;
      } else {
        v[jj] = (float4){0.f, 0.f, 0.f, 0.f};
      }
    }
    // GeM partial over the 8 owned rows (jj=1..8 <-> h0..h0+7)
    float g = 0.f;
    #pragma unroll
    for (int jj = 1; jj <= 8; ++jj) {
      float cx = fmaxf(v[jj].x, 1e-6f), cy = fmaxf(v[jj].y, 1e-6f);
      float cz = fmaxf(v[jj].z, 1e-6f), cw = fmaxf(v[jj].w, 1e-6f);
      if (p3) g += cx * cx * cx + cy * cy * cy + cz * cz * cz + cw * cw * cw;
      else    g += __powf(cx, p) + __powf(cy, p) + __powf(cz, p) + __powf(cw, p);
    }
    gp[dj] = g;
    // horizontal 3-tap (in place; rows independent)
    #pragma unroll
    for (int jj = 0; jj < 10; ++jj) {
      float lf = __shfl_up(v[jj].w, 1, 8);
      float rf = __shfl_down(v[jj].x, 1, 8);
      if (w4 == 0) lf = 0.f;
      if (w4 == 7) rf = 0.f;
      float4 h;
      h.x = lf + v[jj].x + v[jj].y;
      h.y = v[jj].x + v[jj].y + v[jj].z;
      h.z = v[jj].y + v[jj].z + v[jj].w;
      h.w = v[jj].z + v[jj].w + rf;
      v[jj] = h;
    }
    // vertical 3-tap + transposed LDS stage (u16 halves of d-pair words)
    u16* sb16 = (u16*)sbox;
    #pragma unroll
    for (int k = 0; k < 8; ++k) {
      float4 b;
      b.x = v[k].x + v[k + 1].x + v[k + 2].x;
      b.y = v[k].y + v[k + 1].y + v[k + 2].y;
      b.z = v[k].z + v[k + 1].z + v[k + 2].z;
      b.w = v[k].w + v[k + 1].w + v[k + 2].w;
      const int rb = k * 32 + wq;
      sb16[(rb + 0) * 68 + dg * 2 + dj] = f2bf(b.x);
      sb16[(rb + 1) * 68 + dg * 2 + dj] = f2bf(b.y);
      sb16[(rb + 2) * 68 + dg * 2 + dj] = f2bf(b.z);
      sb16[(rb + 3) * 68 + dg * 2 + dj] = f2bf(b.w);
    }
  }
  __syncthreads();

  // coalesced writeout: thread t -> one hw row, 128 B
  {
    const u32* src = sbox + t * 34;
    u16* dst = boxT + ((size_t)(n * HW_ + h0 * W_ + t)) * D_ + d0;
    #pragma unroll
    for (int q = 0; q < 8; ++q) {
      uint4 o;
      o.x = src[q * 4 + 0]; o.y = src[q * 4 + 1];
      o.z = src[q * 4 + 2]; o.w = src[q * 4 + 3];
      ((uint4*)dst)[q] = o;
    }
  }

  // GeM reduce over the 8 w4-lanes
  #pragma unroll
  for (int dj = 0; dj < 2; ++dj) {
    float v = gp[dj];
    v += __shfl_xor(v, 1, 8);
    v += __shfl_xor(v, 2, 8);
    v += __shfl_xor(v, 4, 8);
    if (w4 == 0) atomicAdd(&gbuf[n * D_ + d0 + dg * 2 + dj], v);
  }
}

// ---- K3: proj_w fp32 -> bf16 ----
__global__ __launch_bounds__(256) void k_wconv(const float* __restrict__ w, u16* __restrict__ wb) {
  int i = blockIdx.x * 256 + threadIdx.x;
  float4 v = ((const float4*)w)[i];
  u16 r[4] = { f2bf(v.x), f2bf(v.y), f2bf(v.z), f2bf(v.w) };
  *(uint2*)(wb + (size_t)i * 4) = *(const uint2*)r;
}

// ---- K4: GEMM [64 hw] x [512 f] x [K 2048] ----
// A (boxT tile) via LDS, 4-buffer counted-vmcnt pipeline (swizzled as before).
// B (wb) loaded DIRECTLY global->VGPR per wave, register-double-buffered one
// tile ahead (wb is 2 MiB, L2-resident; no LDS, no barrier needed for B).
// Uniform 5 vm-ops/tile/wave: 1 A-stage + 4 B-frag loads.
// Iter kt: stageA(kt+2), loadB(kt+1) -> vmcnt(5) [A(kt),B(kt) retired] ->
// s_barrier -> MFMA(kt). Tail: kt=62 -> vmcnt(4), kt=63 -> vmcnt(0).
__global__ __launch_bounds__(512) void k_gemm(const u16* __restrict__ boxT,
    const u16* __restrict__ wb, const float* __restrict__ bias,
    float* __restrict__ outL) {
  const int n  = blockIdx.x >> 4;
  const int mt = blockIdx.x & 15;
  const int m0 = n * HW_ + mt * 64;
  const int hw0 = mt * 64;
  const int t = threadIdx.x;
  const int lane = t & 63, wv = t >> 6;
  const int r15 = lane & 15, hi = lane >> 4;

  __shared__ __align__(16) float smem_f[128 * 68];   // 34.8 KB; sA aliases first 16 KB
  __shared__ float s_sq[8][64];
  __shared__ float s_rn[64];

  f32x4 acc[4][4];
  #pragma unroll
  for (int a = 0; a < 4; ++a)
    #pragma unroll
    for (int b = 0; b < 4; ++b) acc[a][b] = (f32x4){0.f, 0.f, 0.f, 0.f};

  // A staging (pre-swizzled global source, linear LDS dest; 4 bufs x 4 KB)
  const int kswz = ((lane & 3) ^ ((lane >> 3) & 3)) * 8;
  const u16* asrc = boxT + (size_t)(m0 + (wv & 3) * 16 + (lane >> 2)) * D_ + kswz;
  const int slot = (hi ^ ((r15 >> 1) & 3)) * 8;      // read-side swizzle (elems)

  // B fragment row pointers (direct-to-reg, MFMA B layout: lane holds 16B)
  const u16* brow[4];
  #pragma unroll
  for (int nf = 0; nf < 4; ++nf)
    brow[nf] = wb + (size_t)(wv * 64 + nf * 16 + r15) * D_ + hi * 8;

#define STAGE_A(KT) GLD_LDS16(asrc + (size_t)(KT) * 32, \
    (char*)smem_f + ((KT) & 3) * 4096 + (wv & 3) * 1024)

  STAGE_A(0);
  STAGE_A(1);
  bf16x8 bc[4], bn[4];
  #pragma unroll
  for (int nf = 0; nf < 4; ++nf) bc[nf] = *(const bf16x8*)(brow[nf]);

  for (int kt = 0; kt < 64; ++kt) {
    if (kt + 2 < 64) STAGE_A(kt + 2);
    if (kt + 1 < 64) {
      #pragma unroll
      for (int nf = 0; nf < 4; ++nf)
        bn[nf] = *(const bf16x8*)(brow[nf] + (kt + 1) * 32);
    }
    __builtin_amdgcn_sched_barrier(0);
    if (kt < 62) {
      asm volatile("s_waitcnt vmcnt(5)" ::: "memory");   // A(kt)+B(kt) retired
    } else if (kt == 62) {
      asm volatile("s_waitcnt vmcnt(4)" ::: "memory");   // only B(63) in flight
    } else {
      asm volatile("s_waitcnt vmcnt(0)" ::: "memory");
    }
    __builtin_amdgcn_sched_barrier(0);
    __builtin_amdgcn_s_barrier();                         // A tile kt visible to all waves
    __builtin_amdgcn_sched_barrier(0);

    const u16* sA = (const u16*)((const char*)smem_f + (kt & 3) * 4096);
    bf16x8 af[4];
    #pragma unroll
    for (int mf = 0; mf < 4; ++mf)
      af[mf] = *(const bf16x8*)(sA + (mf * 16 + r15) * 32 + slot);
    #pragma unroll
    for (int mf = 0; mf < 4; ++mf)
      #pragma unroll
      for (int nf = 0; nf < 4; ++nf)
        acc[mf][nf] = __builtin_amdgcn_mfma_f32_16x16x32_bf16(af[mf], bc[nf], acc[mf][nf], 0, 0, 0);
    #pragma unroll
    for (int nf = 0; nf < 4; ++nf) bc[nf] = bn[nf];
  }
#undef STAGE_A

  // epilogue: bias, per-row (hw) l2 norm over all 512 f, transposed store
  float badd[4];
  #pragma unroll
  for (int nf = 0; nf < 4; ++nf) badd[nf] = bias[wv * 64 + nf * 16 + r15];
  #pragma unroll
  for (int mf = 0; mf < 4; ++mf)
    #pragma unroll
    for (int nf = 0; nf < 4; ++nf)
      #pragma unroll
      for (int j = 0; j < 4; ++j) acc[mf][nf][j] += badd[nf];

  #pragma unroll
  for (int mf = 0; mf < 4; ++mf)
    #pragma unroll
    for (int j = 0; j < 4; ++j) {
      float s = 0.f;
      #pragma unroll
      for (int nf = 0; nf < 4; ++nf) { float v = acc[mf][nf][j]; s += v * v; }
      s += __shfl_xor(s, 1); s += __shfl_xor(s, 2); s += __shfl_xor(s, 4); s += __shfl_xor(s, 8);
      if ((lane & 15) == 0) s_sq[wv][mf * 16 + hi * 4 + j] = s;
    }
  __syncthreads();
  if (t < 64) {
    float s = 0.f;
    #pragma unroll
    for (int w8 = 0; w8 < 8; ++w8) s += s_sq[w8][t];
    s_rn[t] = 1.0f / fmaxf(sqrtf(s), 1e-12f);
  }
  __syncthreads();

  float* ct = smem_f;   // [128 f-rows][68] fp32
  for (int nf = 0; nf < 4; ++nf) {
    const int fi = wv * 16 + r15;
    #pragma unroll
    for (int mf = 0; mf < 4; ++mf)
      #pragma unroll
      for (int j = 0; j < 4; ++j) {
        int m = mf * 16 + hi * 4 + j;
        ct[fi * 68 + m] = acc[mf][nf][j] * s_rn[m];
      }
    __syncthreads();
    {
      int fr = t >> 2, mq = t & 3;
      int f = (fr >> 4) * 64 + nf * 16 + (fr & 15);
      float* dst = outL + ((size_t)(n * F_ + f)) * HW_ + hw0 + mq * 16;
      const float* srcp = ct + fr * 68 + mq * 16;
      float4 a0 = *(const float4*)(srcp);
      float4 a1 = *(const float4*)(srcp + 4);
      float4 a2 = *(const float4*)(srcp + 8);
      float4 a3 = *(const float4*)(srcp + 12);
      *(float4*)(dst) = a0; *(float4*)(dst + 4) = a1;
      *(float4*)(dst + 8) = a2; *(float4*)(dst + 12) = a3;
    }
    __syncthreads();
  }
}

// ---- K5: GeM finalize: gg = (gbuf/1024)^(1/p) ----
__global__ __launch_bounds__(256) void k_gem_fin(const float* __restrict__ gbuf,
    const float* __restrict__ pvec, float* __restrict__ gg) {
  int i = blockIdx.x * 256 + threadIdx.x;
  float p = pvec[0];
  float m = gbuf[i] * (1.0f / 1024.0f);
  gg[i] = (p == 3.0f) ? cbrtf(m) : powf(m, 1.0f / p);
}

// ---- K6: gproj[n][f] = dot(gg[n], W[f]) + b[f] ----
__global__ __launch_bounds__(256) void k_gproj(const float* __restrict__ w,
    const float* __restrict__ bias, const float* __restrict__ gg,
    float* __restrict__ gproj) {
  const int f = blockIdx.x;
  const int t = threadIdx.x;
  float wreg[8];
  #pragma unroll
  for (int j = 0; j < 8; ++j) wreg[j] = w[(size_t)f * D_ + t + j * 256];
  __shared__ float red[4];
  const int lane = t & 63, wv = t >> 6;
  for (int n = 0; n < N_; ++n) {
    float s = 0.f;
    #pragma unroll
    for (int j = 0; j < 8; ++j) s += wreg[j] * gg[n * D_ + t + j * 256];
    #pragma unroll
    for (int off = 32; off >= 1; off >>= 1) s += __shfl_down(s, off);
    if (lane == 0) red[wv] = s;
    __syncthreads();
    if (t == 0) gproj[n * F_ + f] = red[0] + red[1] + red[2] + red[3] + bias[f];
    __syncthreads();
  }
}

// ---- K7: l2norm g rows -> d_out[0:8192] ----
__global__ __launch_bounds__(512) void k_gnorm(const float* __restrict__ gproj, float* __restrict__ outg) {
  const int n = blockIdx.x;
  const int t = threadIdx.x;
  float v = gproj[n * F_ + t];
  float s = v * v;
  const int lane = t & 63, wv = t >> 6;
  #pragma unroll
  for (int off = 32; off >= 1; off >>= 1) s += __shfl_down(s, off);
  __shared__ float red[8];
  __shared__ float rtot;
  if (lane == 0) red[wv] = s;
  __syncthreads();
  if (t == 0) {
    float a = 0.f;
    #pragma unroll
    for (int i = 0; i < 8; ++i) a += red[i];
    rtot = 1.0f / fmaxf(sqrtf(a), 1e-12f);
  }
  __syncthreads();
  outg[n * F_ + t] = v * rtot;
}

extern "C" void kernel_launch(void* const* d_in, const int* in_sizes, int n_in,
                              void* d_out, int out_size, void* d_ws, size_t ws_size,
                              hipStream_t stream) {
  const float* x  = (const float*)d_in[0];
  const float* pw = (const float*)d_in[1];
  const float* pb = (const float*)d_in[2];
  const float* pv = (const float*)d_in[3];
  float* out = (float*)d_out;

  char* ws = (char*)d_ws;
  float* sumsq = (float*)ws;                                   // 64 KB
  float* gbuf  = (float*)(ws + 65536);                         // 128 KB (contiguous after sumsq)
  float* gg    = (float*)(ws + 65536 + 131072);                // 128 KB
  float* gproj = (float*)(ws + 65536 + 2 * 131072);            // 32 KB
  u16*   wb    = (u16*)(ws + 65536 + 2 * 131072 + 32768);      // 2 MiB
  u16*   boxT  = (u16*)(ws + 4u * 1024u * 1024u);              // 64 MiB: [16384 rows][2048] bf16

  k_zero<<<dim3(48), dim3(256), 0, stream>>>(sumsq);           // sumsq + gbuf (192 KB)
  k_sumsq<<<dim3(16, 32), dim3(256), 0, stream>>>(x, sumsq);
  k_wconv<<<dim3(1024), dim3(256), 0, stream>>>(pw, wb);
  k_box3<<<dim3(16, 4, 32), dim3(256), 0, stream>>>(x, sumsq, pv, gbuf, boxT);
  k_gem_fin<<<dim3(128), dim3(256), 0, stream>>>(gbuf, pv, gg);
  k_gproj<<<dim3(512), dim3(256), 0, stream>>>(pw, pb, gg, gproj);
  k_gnorm<<<dim3(16), dim3(512), 0, stream>>>(gproj, out);
  k_gemm<<<dim3(256), dim3(512), 0, stream>>>(boxT, wb, pb, out + N_ * F_);
}

// Round 8
// 151.370 us; speedup vs baseline: 1.2508x; 1.2508x over previous
//
#include <hip/hip_runtime.h>
#include <hip/hip_bf16.h>

#define N_ 16
#define D_ 2048
#define H_ 32
#define W_ 32
#define HW_ 1024
#define F_ 512

typedef unsigned short u16;
typedef unsigned int u32;
typedef __attribute__((ext_vector_type(8))) short bf16x8;
typedef __attribute__((ext_vector_type(4))) float f32x4;

__device__ __forceinline__ u16 f2bf(float f) {
  union { float fv; u32 u; } c; c.fv = f;
  u32 u = c.u;
  u32 r = (u + 0x7fffu + ((u >> 16) & 1u)) >> 16;   // RNE
  return (u16)r;
}

#define GLD_LDS16(gp, lp) __builtin_amdgcn_global_load_lds( \
    (const __attribute__((address_space(1))) void*)(gp), \
    (__attribute__((address_space(3))) void*)(lp), 16, 0, 0)

// ---- K0: zero sumsq+gbuf (192 KB contiguous) ----
__global__ __launch_bounds__(256) void k_zero(float* __restrict__ p) {
  int i = blockIdx.x * 256 + threadIdx.x;
  ((float4*)p)[i] = (float4){0.f, 0.f, 0.f, 0.f};
}

// ---- K1: sum of squares over channel dim -> sumsq[n][hw] (atomic partials) ----
__global__ __launch_bounds__(256) void k_sumsq(const float* __restrict__ x, float* __restrict__ sumsq) {
  const int n = blockIdx.x;        // 16
  const int dc = blockIdx.y;       // 32 chunks x 64 d
  const int t = threadIdx.x;
  const float* xp = x + ((size_t)n * D_ + (size_t)dc * 64) * HW_;
  float s0 = 0.f, s1 = 0.f, s2 = 0.f, s3 = 0.f;
  for (int d = 0; d < 64; ++d) {
    const float* row = xp + (size_t)d * HW_;
    float v0 = row[t], v1 = row[t + 256], v2 = row[t + 512], v3 = row[t + 768];
    s0 += v0 * v0; s1 += v1 * v1; s2 += v2 * v2; s3 += v3 * v3;
  }
  atomicAdd(&sumsq[n * HW_ + t      ], s0);
  atomicAdd(&sumsq[n * HW_ + t + 256], s1);
  atomicAdd(&sumsq[n * HW_ + t + 512], s2);
  atomicAdd(&sumsq[n * HW_ + t + 768], s3);
}

// ---- K2: register-resident separable 3x3 box + GeM partials ----
// grid (n=16, ht=8, dc=32); block 256. Output written in MFMA-fragment-packed
// layout: packA[mt][kt][mf][lane][8] u16, lane = hi*16 + r15.
__global__ __launch_bounds__(256) void k_box2(const float* __restrict__ x,
    const float* __restrict__ sumsq, const float* __restrict__ pvec,
    float* __restrict__ gbuf, u16* __restrict__ packA) {
  const int n = blockIdx.x, ht = blockIdx.y, dc = blockIdx.z;
  const int h0 = ht * 4, d0 = dc * 64;
  const int t = threadIdx.x;
  const int w = t & 31, g = t >> 5;
  const float p = pvec[0];
  const bool p3 = (p == 3.0f);

  __shared__ __align__(16) u16 sbox[128 * 68];   // [hw 128][d 64 pad->68]

  float rn[6];
  #pragma unroll
  for (int jj = 0; jj < 6; ++jj) {
    int hp = h0 - 1 + jj;
    float r = 0.f;
    if (hp >= 0 && hp < H_) r = 1.0f / fmaxf(sqrtf(sumsq[n * HW_ + hp * W_ + w]), 1e-12f);
    rn[jj] = r;
  }

  float s[8];
  #pragma unroll
  for (int j = 0; j < 8; ++j) s[j] = 0.f;

  #pragma unroll 2
  for (int j = 0; j < 8; ++j) {
    const int d = d0 + g * 8 + j;
    const float* col = x + ((size_t)(n * D_ + d)) * HW_ + w;
    float v[6];
    #pragma unroll
    for (int jj = 0; jj < 6; ++jj) {
      int hp = h0 - 1 + jj;
      float xv = (hp >= 0 && hp < H_) ? col[hp * W_] : 0.f;
      v[jj] = xv * rn[jj];
    }
    #pragma unroll
    for (int jj = 1; jj <= 4; ++jj) {
      float cv = fmaxf(v[jj], 1e-6f);
      s[j] += p3 ? cv * cv * cv : __powf(cv, p);
    }
    float hs[6];
    #pragma unroll
    for (int jj = 0; jj < 6; ++jj) {
      float l = __shfl_up(v[jj], 1, 32);
      float r = __shfl_down(v[jj], 1, 32);
      if (w == 0) l = 0.f;
      if (w == 31) r = 0.f;
      hs[jj] = l + v[jj] + r;
    }
    #pragma unroll
    for (int k = 0; k < 4; ++k) {
      float b = hs[k] + hs[k + 1] + hs[k + 2];
      sbox[(k * 32 + w) * 68 + g * 8 + j] = f2bf(b);
    }
  }
  __syncthreads();

  // packed writeout: thread -> 32 bf16 of one hw row = frags (kt, hi=0..3)
  {
    const int r = t >> 1, half = t & 1;
    const u16* srcp = sbox + r * 68 + half * 32;
    uint2 a[8];
    #pragma unroll
    for (int q = 0; q < 8; ++q) a[q] = *(const uint2*)(srcp + q * 4);
    const int mt = n * 16 + ht * 2 + (r >> 6);
    const int mf = (r >> 4) & 3, r15 = r & 15;
    const int kt = dc * 2 + half;
    u16* dst = packA + ((size_t)(mt * 64 + kt) * 4 + mf) * 512 + r15 * 8;
    #pragma unroll
    for (int q = 0; q < 4; ++q) {        // q = hi
      uint4 b;
      b.x = a[2 * q].x; b.y = a[2 * q].y; b.z = a[2 * q + 1].x; b.w = a[2 * q + 1].y;
      *(uint4*)(dst + q * 128) = b;      // (hi*16 lanes)*8 elems = 128 u16
    }
  }

  #pragma unroll
  for (int j = 0; j < 8; ++j) {
    float v = s[j];
    v += __shfl_xor(v, 16, 32);
    v += __shfl_xor(v, 8, 32);
    v += __shfl_xor(v, 4, 32);
    v += __shfl_xor(v, 2, 32);
    v += __shfl_xor(v, 1, 32);
    if (w == 0) atomicAdd(&gbuf[n * D_ + d0 + g * 8 + j], v);
  }
}

// ---- K3: proj_w fp32 -> bf16, fragment-packed: packB[wv][kt][nf][lane][8] ----
// 131072 threads total (512 blocks x 256), 8 elems (16B) out each.
__global__ __launch_bounds__(256) void k_wconv(const float* __restrict__ w, u16* __restrict__ packB) {
  const int i = blockIdx.x * 256 + threadIdx.x;   // 0..131071
  const int lane = i & 63, nf = (i >> 6) & 3, kt = (i >> 8) & 63, wq = i >> 14;  // wq 0..7
  const int r15 = lane & 15, hi = lane >> 4;
  const int f = wq * 64 + nf * 16 + r15;
  const int k = kt * 32 + hi * 8;
  const float* src = w + (size_t)f * D_ + k;
  float4 v0 = *(const float4*)(src);
  float4 v1 = *(const float4*)(src + 4);
  u16 r[8] = { f2bf(v0.x), f2bf(v0.y), f2bf(v0.z), f2bf(v0.w),
               f2bf(v1.x), f2bf(v1.y), f2bf(v1.z), f2bf(v1.w) };
  *(uint4*)(packB + (size_t)i * 8) = *(const uint4*)r;
}

// ---- K4: GEMM [64 hw] x [512 f] x [K 2048], packed operands ----
// 4-buf A via global_load_lds, B->reg lead-1, counted vmcnt 5/4/0, one
// s_barrier per step; ALL loads contiguous 1KB dwordx4; ds_reads lane-linear.
__global__ __launch_bounds__(512) void k_gemm(const u16* __restrict__ packA,
    const u16* __restrict__ packB, const float* __restrict__ bias,
    float* __restrict__ outL) {
  const int n  = blockIdx.x >> 4;
  const int mtl = blockIdx.x & 15;
  const int mt = blockIdx.x;            // global 64-row tile index
  const int hw0 = mtl * 64;
  const int t = threadIdx.x;
  const int lane = t & 63, wv = t >> 6;
  const int r15 = lane & 15, hi = lane >> 4;

  __shared__ __align__(16) float smem_f[128 * 68];   // 34.8 KB; A bufs alias first 16 KB
  __shared__ float s_sq[8][64];
  __shared__ float s_rn[64];

  f32x4 acc[4][4];
  #pragma unroll
  for (int a = 0; a < 4; ++a)
    #pragma unroll
    for (int b = 0; b < 4; ++b) acc[a][b] = (f32x4){0.f, 0.f, 0.f, 0.f};

  // A stage source: contiguous 1KB per (kt, mf-chunk); wave stages chunk (wv&3)
  const u16* asrc = packA + ((size_t)(mt * 64) * 4 + (wv & 3)) * 512 + lane * 8;
  // B fragments: contiguous 1KB each
  const u16* bbase = packB + (size_t)wv * 131072 + lane * 8;

#define STAGE_A(KT) GLD_LDS16(asrc + (size_t)(KT) * 2048, \
    (char*)smem_f + ((KT) & 3) * 4096 + (wv & 3) * 1024)

  STAGE_A(0);
  STAGE_A(1);
  bf16x8 bc[4], bn[4];
  #pragma unroll
  for (int nf = 0; nf < 4; ++nf) bc[nf] = *(const bf16x8*)(bbase + nf * 512);

  for (int kt = 0; kt < 64; ++kt) {
    if (kt + 2 < 64) STAGE_A(kt + 2);
    if (kt + 1 < 64) {
      #pragma unroll
      for (int nf = 0; nf < 4; ++nf)
        bn[nf] = *(const bf16x8*)(bbase + ((kt + 1) * 4 + nf) * 512);
    }
    __builtin_amdgcn_sched_barrier(0);
    if (kt < 62) {
      asm volatile("s_waitcnt vmcnt(5)" ::: "memory");   // A(kt)+B(kt) retired
    } else if (kt == 62) {
      asm volatile("s_waitcnt vmcnt(4)" ::: "memory");
    } else {
      asm volatile("s_waitcnt vmcnt(0)" ::: "memory");
    }
    __builtin_amdgcn_sched_barrier(0);
    __builtin_amdgcn_s_barrier();                         // A tile kt visible
    __builtin_amdgcn_sched_barrier(0);

    const u16* sA = (const u16*)((const char*)smem_f + (kt & 3) * 4096);
    bf16x8 af[4];
    #pragma unroll
    for (int mf = 0; mf < 4; ++mf)
      af[mf] = *(const bf16x8*)(sA + mf * 512 + lane * 8);
    #pragma unroll
    for (int mf = 0; mf < 4; ++mf)
      #pragma unroll
      for (int nf = 0; nf < 4; ++nf)
        acc[mf][nf] = __builtin_amdgcn_mfma_f32_16x16x32_bf16(af[mf], bc[nf], acc[mf][nf], 0, 0, 0);
    #pragma unroll
    for (int nf = 0; nf < 4; ++nf) bc[nf] = bn[nf];
  }
#undef STAGE_A

  // epilogue: bias, per-row (hw) l2 norm over all 512 f, transposed store
  float badd[4];
  #pragma unroll
  for (int nf = 0; nf < 4; ++nf) badd[nf] = bias[wv * 64 + nf * 16 + r15];
  #pragma unroll
  for (int mf = 0; mf < 4; ++mf)
    #pragma unroll
    for (int nf = 0; nf < 4; ++nf)
      #pragma unroll
      for (int j = 0; j < 4; ++j) acc[mf][nf][j] += badd[nf];

  #pragma unroll
  for (int mf = 0; mf < 4; ++mf)
    #pragma unroll
    for (int j = 0; j < 4; ++j) {
      float s = 0.f;
      #pragma unroll
      for (int nf = 0; nf < 4; ++nf) { float v = acc[mf][nf][j]; s += v * v; }
      s += __shfl_xor(s, 1); s += __shfl_xor(s, 2); s += __shfl_xor(s, 4); s += __shfl_xor(s, 8);
      if ((lane & 15) == 0) s_sq[wv][mf * 16 + hi * 4 + j] = s;
    }
  __syncthreads();
  if (t < 64) {
    float s = 0.f;
    #pragma unroll
    for (int w8 = 0; w8 < 8; ++w8) s += s_sq[w8][t];
    s_rn[t] = 1.0f / fmaxf(sqrtf(s), 1e-12f);
  }
  __syncthreads();

  float* ct = smem_f;   // [128 f-rows][68] fp32
  for (int nf = 0; nf < 4; ++nf) {
    const int fi = wv * 16 + r15;
    #pragma unroll
    for (int mf = 0; mf < 4; ++mf)
      #pragma unroll
      for (int j = 0; j < 4; ++j) {
        int m = mf * 16 + hi * 4 + j;
        ct[fi * 68 + m] = acc[mf][nf][j] * s_rn[m];
      }
    __syncthreads();
    {
      int fr = t >> 2, mq = t & 3;
      int f = (fr >> 4) * 64 + nf * 16 + (fr & 15);
      float* dst = outL + ((size_t)(n * F_ + f)) * HW_ + hw0 + mq * 16;
      const float* srcp = ct + fr * 68 + mq * 16;
      float4 a0 = *(const float4*)(srcp);
      float4 a1 = *(const float4*)(srcp + 4);
      float4 a2 = *(const float4*)(srcp + 8);
      float4 a3 = *(const float4*)(srcp + 12);
      *(float4*)(dst) = a0; *(float4*)(dst + 4) = a1;
      *(float4*)(dst + 8) = a2; *(float4*)(dst + 12) = a3;
    }
    __syncthreads();
  }
}

// ---- K5: GeM finalize: gg = (gbuf/1024)^(1/p) ----
__global__ __launch_bounds__(256) void k_gem_fin(const float* __restrict__ gbuf,
    const float* __restrict__ pvec, float* __restrict__ gg) {
  int i = blockIdx.x * 256 + threadIdx.x;
  float p = pvec[0];
  float m = gbuf[i] * (1.0f / 1024.0f);
  gg[i] = (p == 3.0f) ? cbrtf(m) : powf(m, 1.0f / p);
}

// ---- K6: gproj[n][f] = dot(gg[n], W[f]) + b[f] ----
__global__ __launch_bounds__(256) void k_gproj(const float* __restrict__ w,
    const float* __restrict__ bias, const float* __restrict__ gg,
    float* __restrict__ gproj) {
  const int f = blockIdx.x;
  const int t = threadIdx.x;
  float wreg[8];
  #pragma unroll
  for (int j = 0; j < 8; ++j) wreg[j] = w[(size_t)f * D_ + t + j * 256];
  __shared__ float red[4];
  const int lane = t & 63, wv = t >> 6;
  for (int n = 0; n < N_; ++n) {
    float s = 0.f;
    #pragma unroll
    for (int j = 0; j < 8; ++j) s += wreg[j] * gg[n * D_ + t + j * 256];
    #pragma unroll
    for (int off = 32; off >= 1; off >>= 1) s += __shfl_down(s, off);
    if (lane == 0) red[wv] = s;
    __syncthreads();
    if (t == 0) gproj[n * F_ + f] = red[0] + red[1] + red[2] + red[3] + bias[f];
    __syncthreads();
  }
}

// ---- K7: l2norm g rows -> d_out[0:8192] ----
__global__ __launch_bounds__(512) void k_gnorm(const float* __restrict__ gproj, float* __restrict__ outg) {
  const int n = blockIdx.x;
  const int t = threadIdx.x;
  float v = gproj[n * F_ + t];
  float s = v * v;
  const int lane = t & 63, wv = t >> 6;
  #pragma unroll
  for (int off = 32; off >= 1; off >>= 1) s += __shfl_down(s, off);
  __shared__ float red[8];
  __shared__ float rtot;
  if (lane == 0) red[wv] = s;
  __syncthreads();
  if (t == 0) {
    float a = 0.f;
    #pragma unroll
    for (int i = 0; i < 8; ++i) a += red[i];
    rtot = 1.0f / fmaxf(sqrtf(a), 1e-12f);
  }
  __syncthreads();
  outg[n * F_ + t] = v * rtot;
}

extern "C" void kernel_launch(void* const* d_in, const int* in_sizes, int n_in,
                              void* d_out, int out_size, void* d_ws, size_t ws_size,
                              hipStream_t stream) {
  const float* x  = (const float*)d_in[0];
  const float* pw = (const float*)d_in[1];
  const float* pb = (const float*)d_in[2];
  const float* pv = (const float*)d_in[3];
  float* out = (float*)d_out;

  char* ws = (char*)d_ws;
  float* sumsq = (float*)ws;                                   // 64 KB
  float* gbuf  = (float*)(ws + 65536);                         // 128 KB
  float* gg    = (float*)(ws + 65536 + 131072);                // 128 KB
  float* gproj = (float*)(ws + 65536 + 2 * 131072);            // 32 KB
  u16*   packB = (u16*)(ws + 65536 + 2 * 131072 + 32768);      // 2 MiB
  u16*   packA = (u16*)(ws + 4u * 1024u * 1024u);              // 64 MiB

  k_zero<<<dim3(48), dim3(256), 0, stream>>>(sumsq);           // sumsq + gbuf
  k_sumsq<<<dim3(16, 32), dim3(256), 0, stream>>>(x, sumsq);
  k_wconv<<<dim3(512), dim3(256), 0, stream>>>(pw, packB);
  k_box2<<<dim3(16, 8, 32), dim3(256), 0, stream>>>(x, sumsq, pv, gbuf, packA);
  k_gem_fin<<<dim3(128), dim3(256), 0, stream>>>(gbuf, pv, gg);
  k_gproj<<<dim3(512), dim3(256), 0, stream>>>(pw, pb, gg, gproj);
  k_gnorm<<<dim3(16), dim3(512), 0, stream>>>(gproj, out);
  k_gemm<<<dim3(256), dim3(512), 0, stream>>>(packA, packB, pb, out + N_ * F_);
}